// Round 8
// baseline (43.451 us; speedup 1.0000x reference)
//
#include <hip/hip_runtime.h>

constexpr int B   = 1024;
constexpr int T   = 8192;
constexpr int MS  = 128;
constexpr int NF4 = T / 2;     // 4096 float4 positions per row (2 t's each)

// Padded LDS index for prefix entry k (k in [0, 4096]):
// idx(k) = k + (k>>4). For k = 16*tid + j (j<16) this is 17*tid + j.
__device__ __forceinline__ int pidx(int k) { return k + (k >> 4); }

// Fused: one block (256 threads = 4 waves) per batch row + last-block-done
// global reduce. Round-6 lesson: NO __threadfence() (seq_cst agent fence =
// wbl2+inv per wave = L2-invalidate storm). Instead: single-thread relaxed
// agent-scope atomic stores + one ACQ_REL ticket RMW per block; only the
// last block's acquire invalidates, after all streaming is complete.
__global__ __launch_bounds__(256, 4) void provence_fused_kernel(
    const float* __restrict__ rlogits,   // [B]
    const float* __restrict__ rlabels,   // [B]
    const float* __restrict__ logits,    // [B, T, 2]
    const int*   __restrict__ labels,    // [B, MS]
    const int*   __restrict__ bnd,       // [B, MS, 2]
    float*       __restrict__ partial,   // [B*4] (nll, cnt, bce, pad)
    unsigned int* __restrict__ counter,  // zeroed via hipMemsetAsync per call
    float*       __restrict__ out)       // [1]
{
    const int b    = blockIdx.x;
    const int tid  = threadIdx.x;
    const int lane = tid & 63;
    const int wave = tid >> 6;
    const float* row = logits + (size_t)b * T * 2;

    __shared__ float2 E2[NF4 + (NF4 >> 4) + 2];   // ~34.9 KB
    __shared__ float  wtot0[4], wtot1[4];
    __shared__ float  rn[4], rc[4], rb[4];
    __shared__ bool   isLast;

    // ---- Phase 0: metadata; thread 0 computes this row's BCE term ----
    int s_ = -1, e_ = -1, lab_ = 0;
    if (tid < MS) {
        const size_t bm = (size_t)b * MS + tid;
        s_   = bnd[bm * 2 + 0];
        e_   = bnd[bm * 2 + 1];
        lab_ = labels[bm];
    }
    float bce_b = 0.f;
    if (tid == 0) {
        const float x = rlogits[b];
        const float y = rlabels[b];
        const float t = log1pf(expf(-fabsf(x)));
        bce_b = y * (fmaxf(-x, 0.f) + t) + (1.f - y) * (fmaxf(x, 0.f) + t);
    }

    // ---- Phase 1: batch-load chunk (16 float4 in flight), then sum ----
    float4 v[16];
    {
        const float4* p = reinterpret_cast<const float4*>(row) + (size_t)tid * 16;
        #pragma unroll
        for (int j = 0; j < 16; ++j) v[j] = p[j];
    }
    __builtin_amdgcn_sched_barrier(0);   // all 16 loads issued before compute
    float ex0 = 0.f, ex1 = 0.f;
    #pragma unroll
    for (int j = 0; j < 16; ++j) {
        ex0 += v[j].x + v[j].z;
        ex1 += v[j].y + v[j].w;
    }

    // ---- Phase 2: scan of thread totals -> exclusive base; fill E2 ----
    float x0 = ex0, x1 = ex1;
    #pragma unroll
    for (int off = 1; off < 64; off <<= 1) {
        float y0 = __shfl_up(x0, off, 64);
        float y1 = __shfl_up(x1, off, 64);
        if (lane >= off) { x0 += y0; x1 += y1; }
    }
    if (lane == 63) { wtot0[wave] = x0; wtot1[wave] = x1; }
    __syncthreads();
    float pre0 = 0.f, pre1 = 0.f;
    #pragma unroll
    for (int w = 0; w < 3; ++w) {
        if (wave > w) { pre0 += wtot0[w]; pre1 += wtot1[w]; }
    }
    const float incl0 = x0 + pre0, incl1 = x1 + pre1;
    float run0 = incl0 - ex0, run1 = incl1 - ex1;   // exclusive base
    #pragma unroll
    for (int j = 0; j < 16; ++j) {                  // recompute prefix from v[]
        E2[17 * tid + j] = make_float2(run0, run1);
        run0 += v[j].x + v[j].z;
        run1 += v[j].y + v[j].w;
    }
    if (tid == 255) E2[pidx(NF4)] = make_float2(run0, run1);  // k = 4096
    __syncthreads();

    // ---- Phase 3: per-segment NLL (parallel over 128 segments) ----
    float nll = 0.f, cnt = 0.f;
    if (tid < MS && s_ != -1) {
        const int sc = min(max(s_, 0), T);
        const int ec = min(max(e_, 0), T);
        const int cs = sc >> 1;
        const int ce = ec >> 1;

        const float2 Ps = E2[pidx(cs)];
        const float2 Pe = E2[pidx(ce)];
        float q0 = Pe.x - Ps.x;
        float q1 = Pe.y - Ps.y;
        if (sc & 1) {  // subtract element sc-1
            float2 u = *reinterpret_cast<const float2*>(row + (size_t)(sc - 1) * 2);
            q0 -= u.x; q1 -= u.y;
        }
        if (ec & 1) {  // add element ec-1
            float2 u = *reinterpret_cast<const float2*>(row + (size_t)(ec - 1) * 2);
            q0 += u.x; q1 += u.y;
        }

        const int len = ec - sc;
        float p0 = 0.f, p1 = 0.f;
        if (len > 0) {
            const float inv = 1.0f / (float)len;
            p0 = q0 * inv;
            p1 = q1 * inv;
        }
        const float mx  = fmaxf(p0, p1);
        const float lse = mx + logf(expf(p0 - mx) + expf(p1 - mx));
        nll = lse - ((lab_ == 0) ? p0 : p1);
        cnt = 1.0f;
    }

    // ---- Phase 4: block reduce ----
    #pragma unroll
    for (int off = 32; off > 0; off >>= 1) {
        nll += __shfl_down(nll, off, 64);
        cnt += __shfl_down(cnt, off, 64);
    }
    if (lane == 0) { rn[wave] = nll; rc[wave] = cnt; }
    __syncthreads();

    // ---- Phase 5: publish + ticket (thread 0 only; no fences, no inv) ----
    if (tid == 0) {
        const float tn = rn[0] + rn[1] + rn[2] + rn[3];
        const float tc = rc[0] + rc[1] + rc[2] + rc[3];
        __hip_atomic_store(&partial[b * 4 + 0], tn,   __ATOMIC_RELAXED, __HIP_MEMORY_SCOPE_AGENT);
        __hip_atomic_store(&partial[b * 4 + 1], tc,   __ATOMIC_RELAXED, __HIP_MEMORY_SCOPE_AGENT);
        __hip_atomic_store(&partial[b * 4 + 2], bce_b, __ATOMIC_RELAXED, __HIP_MEMORY_SCOPE_AGENT);
        const unsigned int old =
            __hip_atomic_fetch_add(counter, 1u, __ATOMIC_ACQ_REL, __HIP_MEMORY_SCOPE_AGENT);
        isLast = (old == (unsigned int)(B - 1));
    }
    __syncthreads();
    if (!isLast) return;

    // ---- Phase 6: last block reduces all partials (fixed order) ----
    float fn = 0.f, fc = 0.f, fb = 0.f;
    #pragma unroll
    for (int i = 0; i < 4; ++i) {
        const int idx = (tid + i * 256) * 4;
        fn += __hip_atomic_load(&partial[idx + 0], __ATOMIC_RELAXED, __HIP_MEMORY_SCOPE_AGENT);
        fc += __hip_atomic_load(&partial[idx + 1], __ATOMIC_RELAXED, __HIP_MEMORY_SCOPE_AGENT);
        fb += __hip_atomic_load(&partial[idx + 2], __ATOMIC_RELAXED, __HIP_MEMORY_SCOPE_AGENT);
    }
    #pragma unroll
    for (int off = 32; off > 0; off >>= 1) {
        fn += __shfl_down(fn, off, 64);
        fc += __shfl_down(fc, off, 64);
        fb += __shfl_down(fb, off, 64);
    }
    if (lane == 0) { rn[wave] = fn; rc[wave] = fc; rb[wave] = fb; }
    __syncthreads();
    if (tid == 0) {
        const float tn = rn[0] + rn[1] + rn[2] + rn[3];
        const float tc = rc[0] + rc[1] + rc[2] + rc[3];
        const float tb = rb[0] + rb[1] + rb[2] + rb[3];
        const float rank  = tb / (float)B;
        const float prune = (tc > 0.f) ? (tn / tc) : 0.f;
        out[0] = 1.0f * rank + 0.5f * prune;
    }
}

extern "C" void kernel_launch(void* const* d_in, const int* in_sizes, int n_in,
                              void* d_out, int out_size, void* d_ws, size_t ws_size,
                              hipStream_t stream) {
    const float* rlogits = (const float*)d_in[0];  // ranking_logits [B]
    const float* rlabels = (const float*)d_in[1];  // ranking_labels [B]
    const float* plogits = (const float*)d_in[2];  // pruning_logits [B,T,C]
    const int*   plabels = (const int*)  d_in[3];  // pruning_labels [B,MS]
    const int*   bnd     = (const int*)  d_in[4];  // boundaries [B,MS,2]

    float* out     = (float*)d_out;
    float* partial = (float*)d_ws;                         // B*4 floats
    unsigned int* counter =
        (unsigned int*)((char*)d_ws + (size_t)B * 4 * sizeof(float));

    // Counter must be 0 at kernel start on every call (first call sees
    // poisoned d_ws; replays must not inherit state).
    hipMemsetAsync(counter, 0, sizeof(unsigned int), stream);

    provence_fused_kernel<<<B, 256, 0, stream>>>(
        rlogits, rlabels, plogits, plabels, bnd, partial, counter, out);
}

// Round 9
// 19.893 us; speedup vs baseline: 2.1842x; 2.1842x over previous
//
#include <hip/hip_runtime.h>

constexpr int B   = 1024;
constexpr int T   = 8192;
constexpr int MS  = 128;
constexpr int NF4 = T / 2;     // 4096 2-t prefix entries per row

// Padded LDS index for prefix entry k (k in [0, 4096]): idx = k + (k>>4).
__device__ __forceinline__ int pidx(int k) { return k + (k >> 4); }

// One block (512 threads = 8 waves) per batch row: 4 blocks/CU x 8 waves =
// 32 waves/CU (100% occupancy; round-7's 256-thr shape capped at 50%).
// __launch_bounds__(512,8) -> 64-VGPR cap; pair-sum form stays under it.
// Thread tid owns t in [tid*16, tid*16+16) = 8 float4s.
// max_e skip: chunks at/after the last valid segment end are never loaded
// (~12% of bytes); prefix entries beyond max_e are never queried.
__global__ __launch_bounds__(512, 8) void seg_loss_kernel(
    const float* __restrict__ rlogits,   // [B]
    const float* __restrict__ rlabels,   // [B]
    const float* __restrict__ logits,    // [B, T, 2]
    const int*   __restrict__ labels,    // [B, MS]
    const int*   __restrict__ bnd,       // [B, MS, 2]
    float4*      __restrict__ partial)   // [B] (nll, cnt, bce, 0)
{
    const int b    = blockIdx.x;
    const int tid  = threadIdx.x;
    const int lane = tid & 63;
    const int wave = tid >> 6;
    const float* row = logits + (size_t)b * T * 2;

    __shared__ float2 E2[NF4 + (NF4 >> 4) + 2];   // ~34.9 KB
    __shared__ float  wtot0[8], wtot1[8];
    __shared__ float  rn[8], rc[8];
    __shared__ int    wemax[2];

    // ---- Phase 0: metadata; row BCE on thread 0; max valid end ----
    int s_ = -1, e_ = -1, lab_ = 0;
    if (tid < MS) {
        const size_t bm = (size_t)b * MS + tid;
        s_   = bnd[bm * 2 + 0];
        e_   = bnd[bm * 2 + 1];
        lab_ = labels[bm];
    }
    float bce_b = 0.f;
    if (tid == 0) {
        const float x = rlogits[b];
        const float y = rlabels[b];
        const float t = log1pf(expf(-fabsf(x)));
        bce_b = y * (fmaxf(-x, 0.f) + t) + (1.f - y) * (fmaxf(x, 0.f) + t);
    }
    int emax = (tid < MS && s_ != -1) ? min(max(e_, 0), T) : 0;
    #pragma unroll
    for (int off = 32; off > 0; off >>= 1)
        emax = max(emax, __shfl_down(emax, off, 64));
    if (wave < 2 && lane == 0) wemax[wave] = emax;   // segments live in waves 0-1
    __syncthreads();
    const int max_e = max(wemax[0], wemax[1]);

    // ---- Phase 1: per-thread 8 float4 loads (2 batches of 4), pair sums ----
    float2 pair[8];                      // per-float4 (2-t) channel sums
    const int chunk_lo = tid << 4;       // first t of this thread's chunk
    if (chunk_lo < max_e) {
        const float4* p = reinterpret_cast<const float4*>(row) + (size_t)tid * 8;
        #pragma unroll
        for (int g = 0; g < 2; ++g) {
            float4 w0 = p[g * 4 + 0], w1 = p[g * 4 + 1];
            float4 w2 = p[g * 4 + 2], w3 = p[g * 4 + 3];
            pair[g * 4 + 0] = make_float2(w0.x + w0.z, w0.y + w0.w);
            pair[g * 4 + 1] = make_float2(w1.x + w1.z, w1.y + w1.w);
            pair[g * 4 + 2] = make_float2(w2.x + w2.z, w2.y + w2.w);
            pair[g * 4 + 3] = make_float2(w3.x + w3.z, w3.y + w3.w);
        }
    } else {
        #pragma unroll
        for (int j = 0; j < 8; ++j) pair[j] = make_float2(0.f, 0.f);
    }
    float ex0 = 0.f, ex1 = 0.f;
    #pragma unroll
    for (int j = 0; j < 8; ++j) { ex0 += pair[j].x; ex1 += pair[j].y; }

    // ---- Phase 2: scan of thread totals -> exclusive base; fill E2 ----
    float x0 = ex0, x1 = ex1;
    #pragma unroll
    for (int off = 1; off < 64; off <<= 1) {
        float y0 = __shfl_up(x0, off, 64);
        float y1 = __shfl_up(x1, off, 64);
        if (lane >= off) { x0 += y0; x1 += y1; }
    }
    if (lane == 63) { wtot0[wave] = x0; wtot1[wave] = x1; }
    __syncthreads();
    float pre0 = 0.f, pre1 = 0.f;
    #pragma unroll
    for (int w = 0; w < 7; ++w) {
        if (wave > w) { pre0 += wtot0[w]; pre1 += wtot1[w]; }
    }
    float run0 = x0 + pre0 - ex0, run1 = x1 + pre1 - ex1;   // exclusive base
    #pragma unroll
    for (int j = 0; j < 8; ++j) {       // entry k = prefix before float4 k
        const int k = 8 * tid + j;
        E2[pidx(k)] = make_float2(run0, run1);
        run0 += pair[j].x;
        run1 += pair[j].y;
    }
    if (tid == 511) E2[pidx(NF4)] = make_float2(run0, run1);  // k = 4096
    __syncthreads();

    // ---- Phase 3: per-segment NLL (parallel over 128 segments) ----
    float nll = 0.f, cnt = 0.f;
    if (tid < MS && s_ != -1) {
        const int sc = min(max(s_, 0), T);
        const int ec = min(max(e_, 0), T);
        const int cs = sc >> 1;
        const int ce = ec >> 1;

        const float2 Ps = E2[pidx(cs)];
        const float2 Pe = E2[pidx(ce)];
        float q0 = Pe.x - Ps.x;
        float q1 = Pe.y - Ps.y;
        if (sc & 1) {  // subtract element sc-1
            float2 u = *reinterpret_cast<const float2*>(row + (size_t)(sc - 1) * 2);
            q0 -= u.x; q1 -= u.y;
        }
        if (ec & 1) {  // add element ec-1
            float2 u = *reinterpret_cast<const float2*>(row + (size_t)(ec - 1) * 2);
            q0 += u.x; q1 += u.y;
        }

        const int len = ec - sc;
        float p0 = 0.f, p1 = 0.f;
        if (len > 0) {
            const float inv = 1.0f / (float)len;
            p0 = q0 * inv;
            p1 = q1 * inv;
        }
        const float mx  = fmaxf(p0, p1);
        const float lse = mx + logf(expf(p0 - mx) + expf(p1 - mx));
        nll = lse - ((lab_ == 0) ? p0 : p1);
        cnt = 1.0f;
    }

    // ---- Phase 4: block reduce -> partial[b] ----
    #pragma unroll
    for (int off = 32; off > 0; off >>= 1) {
        nll += __shfl_down(nll, off, 64);
        cnt += __shfl_down(cnt, off, 64);
    }
    if (lane == 0) { rn[wave] = nll; rc[wave] = cnt; }
    __syncthreads();
    if (tid == 0) {
        float tn = 0.f, tc = 0.f;
        #pragma unroll
        for (int w = 0; w < 8; ++w) { tn += rn[w]; tc += rc[w]; }
        partial[b] = make_float4(tn, tc, bce_b, 0.f);
    }
}

// Single-block finalize: reduce per-row partials (nll, cnt, bce) -> scalar.
__global__ __launch_bounds__(256) void finalize_kernel(
    const float4* __restrict__ partial,  // [B]
    float*        __restrict__ out)      // [1]
{
    const int tid  = threadIdx.x;
    const int lane = tid & 63;
    const int wave = tid >> 6;

    float nll = 0.f, cnt = 0.f, bce = 0.f;
    #pragma unroll
    for (int i = 0; i < 4; ++i) {
        const float4 p = partial[tid + i * 256];
        nll += p.x; cnt += p.y; bce += p.z;
    }

    #pragma unroll
    for (int off = 32; off > 0; off >>= 1) {
        nll += __shfl_down(nll, off, 64);
        cnt += __shfl_down(cnt, off, 64);
        bce += __shfl_down(bce, off, 64);
    }
    __shared__ float sn[4], sc[4], sb[4];
    if (lane == 0) { sn[wave] = nll; sc[wave] = cnt; sb[wave] = bce; }
    __syncthreads();
    if (tid == 0) {
        const float tn = sn[0] + sn[1] + sn[2] + sn[3];
        const float tc = sc[0] + sc[1] + sc[2] + sc[3];
        const float tb = sb[0] + sb[1] + sb[2] + sb[3];
        const float rank  = tb / (float)B;
        const float prune = (tc > 0.f) ? (tn / tc) : 0.f;
        out[0] = 1.0f * rank + 0.5f * prune;
    }
}

extern "C" void kernel_launch(void* const* d_in, const int* in_sizes, int n_in,
                              void* d_out, int out_size, void* d_ws, size_t ws_size,
                              hipStream_t stream) {
    const float* rlogits = (const float*)d_in[0];  // ranking_logits [B]
    const float* rlabels = (const float*)d_in[1];  // ranking_labels [B]
    const float* plogits = (const float*)d_in[2];  // pruning_logits [B,T,C]
    const int*   plabels = (const int*)  d_in[3];  // pruning_labels [B,MS]
    const int*   bnd     = (const int*)  d_in[4];  // boundaries [B,MS,2]

    float*  out     = (float*)d_out;
    float4* partial = (float4*)d_ws;   // B float4s, fully written by kernel 1

    seg_loss_kernel<<<B, 512, 0, stream>>>(rlogits, rlabels, plogits,
                                           plabels, bnd, partial);
    finalize_kernel<<<1, 256, 0, stream>>>(partial, out);
}